// Round 10
// baseline (217.642 us; speedup 1.0000x reference)
//
#include <hip/hip_runtime.h>
#include <hip/hip_bf16.h>

// Problem: B=4, L=4096, DH=1024, T=1024, DG=768, P=256
// Inputs fp32 + bool mask (width auto-detect); OUTPUT fp32.
//
// MASK COMPACTION: ~50% of l are masked; masked columns have alpha == 0
// exactly. A single scan kernel (one block/batch) builds the valid-l list
// idx[b][c], Lc, Lc_pad ONCE; all passes work in compact index space.
//
// 5-DISPATCH PIPELINE:
//   1) scan:     width-detect + valid-l scan + rowsum zero (one block/batch)
//   2) prep_all: H gather/convert/transpose (reads idx) + cvt Wk/Wq/G
//   3) qk_gemm:  Q = Gbf@Wq^T and K_c = Hbf_c@Wk^T in one launch
//   4) s_gemm:   P_c = exp(Q@K_c^T/16), cols >= Lc zeroed by compare;
//                fp32 rowsum atomics
//   5) z_gemm:   Z = (P_c @ Ht_c^T) * (1/rowsum), M-SPLIT 64x128 tiles,
//                FULL compact K per WG -> normalized direct fp32 store.
//
// GEMM K-loop: COUNTED-VMCNT pipeline (T4), 3 buffers, prefetch depth 2;
// GRANULE-XOR LDS swizzle (conflicts == 0, verified); bf16 epilogues via
// LDS-staged 16B/lane vectorized writeout; XCD-chunked blockIdx swizzle (T1).
// Round-10: Z uses KTP=2 (2 k-tiles per phase, 3 super-buffers, 72 KB LDS,
// still 2 WGs/CU) to HALVE barrier+vmcnt count — our small-shape GEMMs are
// phase-overhead-bound (~30% MfmaUtil regime), and the grid caps occupancy
// at 2 WGs/CU so the extra LDS is free. Z fp32 writeout now LDS-staged
// ([64][136] f32) -> global_store_dwordx4 at 128B/row segments (was 32
// scalar dword stores at 64B segments — same G13 fix as the bf16 path).

typedef __attribute__((ext_vector_type(8))) short short8;   // 8 bf16 = 4 VGPRs
typedef __attribute__((ext_vector_type(4))) float f32x4;

static __device__ __forceinline__ unsigned short bf16bits(float x) {
    __hip_bfloat16 b = __float2bfloat16(x);
    return *(unsigned short*)&b;
}

// Async global->LDS, 16 B per lane. LDS dest = wave-uniform base + lane*16.
static __device__ __forceinline__ void gload_lds16(const __hip_bfloat16* g,
                                                   __hip_bfloat16* l)
{
    auto gp = (const __attribute__((address_space(1))) unsigned int*)(uintptr_t)g;
    auto lp = (__attribute__((address_space(3))) unsigned int*)(unsigned int)(uintptr_t)l;
    __builtin_amdgcn_global_load_lds(gp, lp, 16, 0, 0);
}

// ---------------------------------------------------------------------------
// Fused: mask width detect + valid-l compaction scan + rowsum zero.
// One block per batch (runs ONCE; consumers read the tiny outputs).
// ---------------------------------------------------------------------------
__global__ __launch_bounds__(256)
void scan_kernel(const void* __restrict__ mask,
                 unsigned short* __restrict__ idx,
                 int* __restrict__ lc, int* __restrict__ lcpad,
                 float* __restrict__ rowsum, int L, int T, int B)
{
    const int b = blockIdx.x;
    const int tid = threadIdx.x;

    // zero this batch's rowsum slice (S-pass accumulates atomically)
    for (int i = tid; i < T; i += 256) rowsum[(long)b * T + i] = 0.f;

    // --- width detection over the whole mask buffer (B*L bools) ---
    const unsigned char*  m8g  = (const unsigned char*)mask;
    const unsigned short* m16g = (const unsigned short*)mask;
    const unsigned int*   m32g = (const unsigned int*)mask;
    __shared__ int c1, c2, c4, c8, cp, wsh;
    if (tid == 0) { c1 = c2 = c4 = c8 = cp = 0; }
    __syncthreads();
    {
        const int N = B * L;   // 16384
        int l1 = 0, l2 = 0, l4 = 0, l8 = 0, lp = 0;
        for (int i = tid; i < N; i += 256) l1 += (m8g[i] != 0);
        for (int i = tid; i < N / 2; i += 256) {
            l2 += (m16g[i] != 0);
            lp += ((m8g[2 * i] != 0) == (m8g[2 * i + 1] != 0));
        }
        for (int i = tid; i < N / 4; i += 256) l4 += (m32g[i] != 0);
        for (int i = tid; i < N / 8; i += 256) l8 += ((m32g[2 * i] | m32g[2 * i + 1]) != 0);
        atomicAdd(&c1, l1); atomicAdd(&c2, l2); atomicAdd(&c4, l4);
        atomicAdd(&c8, l8); atomicAdd(&cp, lp);
    }
    __syncthreads();
    if (tid == 0) {
        const float f1 = fabsf(c1 / 16384.f - 0.5f);
        const float f2 = fabsf(c2 / 8192.f  - 0.5f);
        const float f4 = fabsf(c4 / 4096.f  - 0.5f);
        const float f8 = fabsf(c8 / 2048.f  - 0.5f);
        int w = 1; float best = f1;
        if (f2 < best) { best = f2; w = 2; }
        if (f4 < best) { best = f4; w = 4; }
        if (f8 < best) { best = f8; w = 8; }
        if (w == 1 && cp > 7400) w = 2;
        wsh = w;
    }
    __syncthreads();
    const int w = wsh;

    // --- compaction scan for batch b (16 l's per thread) ---
    const unsigned char*  m8  = (const unsigned char*)mask;
    const unsigned short* m16 = (const unsigned short*)mask;
    const unsigned int*   m32 = (const unsigned int*)mask;
    const uint2*          m64 = (const uint2*)mask;
    bool v[16];
    int cnt = 0;
    #pragma unroll
    for (int i = 0; i < 16; ++i) {
        const int l = tid * 16 + i;
        const long mi = (long)b * L + l;
        bool masked;
        if (w == 1)      masked = m8[mi] != 0;
        else if (w == 2) masked = m16[mi] != 0;
        else if (w == 4) masked = m32[mi] != 0;
        else             { uint2 q = m64[mi]; masked = (q.x | q.y) != 0; }
        v[i] = !masked;
        cnt += v[i] ? 1 : 0;
    }
    __shared__ int waveTot[4];
    int pre = cnt;
    #pragma unroll
    for (int off = 1; off < 64; off <<= 1) {
        const int t = __shfl_up(pre, off, 64);
        if ((tid & 63) >= off) pre += t;
    }
    if ((tid & 63) == 63) waveTot[tid >> 6] = pre;
    __syncthreads();
    int waveOff = 0;
    for (int wv = 0; wv < (tid >> 6); ++wv) waveOff += waveTot[wv];
    int o = waveOff + pre - cnt;          // exclusive prefix for this thread
    #pragma unroll
    for (int i = 0; i < 16; ++i)
        if (v[i]) idx[(long)b * L + (o++)] = (unsigned short)(tid * 16 + i);
    if (tid == 255) {
        const int total = waveOff + pre;
        lc[b] = total;
        lcpad[b] = (total + 127) & ~127;
    }
}

// ---------------------------------------------------------------------------
// Fused prep: blocks [0, 4096) = H gather/convert/transpose (64x64 tiles,
// reads the global idx buffer); blocks [4096, 7616) = cvt Wk/Wq/G.
// ---------------------------------------------------------------------------
__global__ __launch_bounds__(256)
void prep_all_kernel(const float* __restrict__ H,
                     __hip_bfloat16* __restrict__ Hbf,
                     __hip_bfloat16* __restrict__ Ht,
                     const unsigned short* __restrict__ idx,
                     const int* __restrict__ lc, const int* __restrict__ lcpad,
                     const float* __restrict__ Wk, unsigned short* __restrict__ Wkbf,
                     const float* __restrict__ Wq, unsigned short* __restrict__ Wqbf,
                     const float* __restrict__ G,  unsigned short* __restrict__ Gbf,
                     int L, int D)
{
    __shared__ __align__(16) __hip_bfloat16 tile[64][72];  // [d][c], pad 8
    int id = blockIdx.x;
    if (id < 4096) {
        // --- h gather: c-tile (id&63), d-tile ((id>>6)&15), b (id>>10) ---
        const int b  = id >> 10;
        const int c0 = (id & 63) * 64;
        if (c0 >= lcpad[b]) return;       // uniform: beyond padded extent
        const int d0 = ((id >> 6) & 15) * 64;
        const int Lcb = lc[b];
        const float* Hb = H + (long)b * L * D;
        __hip_bfloat16* Hbfb = Hbf + (long)b * L * D;
        __hip_bfloat16* Htb  = Ht  + (long)b * D * L;
        const int tx = threadIdx.x & 15, ty = threadIdx.x >> 4;  // 16 x 16
        #pragma unroll
        for (int p = 0; p < 4; ++p) {
            const int row = ty + p * 16;     // compact index within tile
            const int c = c0 + row;
            float4 v = {0.f, 0.f, 0.f, 0.f};
            if (c < Lcb) {
                const int l = idx[(long)b * L + c];
                v = *(const float4*)(&Hb[(long)l * D + d0 + tx * 4]);
            }
            ushort4 o;
            o.x = bf16bits(v.x); o.y = bf16bits(v.y);
            o.z = bf16bits(v.z); o.w = bf16bits(v.w);
            *(ushort4*)(&Hbfb[(long)c * D + d0 + tx * 4]) = o;
            tile[tx * 4 + 0][row] = __float2bfloat16(v.x);
            tile[tx * 4 + 1][row] = __float2bfloat16(v.y);
            tile[tx * 4 + 2][row] = __float2bfloat16(v.z);
            tile[tx * 4 + 3][row] = __float2bfloat16(v.w);
        }
        __syncthreads();
        const int ll = threadIdx.x & 7;      // 8 threads x 16B = 128B per d-row
        const int dq = threadIdx.x >> 3;     // 32 d-rows per pass
        #pragma unroll
        for (int q = 0; q < 2; ++q) {
            const int dd = dq + q * 32;
            const short8 v = *(const short8*)(&tile[dd][ll * 8]);
            *(short8*)(&Htb[(long)(d0 + dd) * L + c0 + ll * 8]) = v;
        }
        return;
    }
    // --- cvt ranges ---
    id -= 4096;
    const float* in; unsigned short* out; int n4;
    if (id < 256)       { in = Wk; out = Wkbf; n4 = (256 * 1024) / 4; }
    else if (id < 448)  { id -= 256; in = Wq; out = Wqbf; n4 = (256 * 768) / 4; }
    else                { id -= 448; in = G;  out = Gbf;  n4 = (4 * 1024 * 768) / 4; }
    const int i = id * 256 + threadIdx.x;
    if (i >= n4) return;
    float4 v = ((const float4*)in)[i];
    ushort4 o;
    o.x = bf16bits(v.x); o.y = bf16bits(v.y);
    o.z = bf16bits(v.z); o.w = bf16bits(v.w);
    ((ushort4*)out)[i] = o;
}

// ---------------------------------------------------------------------------
// GEMM body: C[M,N] (op)= scale * A[M,K] @ Bm[N,K]^T  (bf16 row-major)
// Tile BM x 128, 4 waves. BM=128: wave 64x64, 4x4 frags, 4 gloads/tile.
// BM=64: wave 32x64, 2x4 frags, 3 gloads/tile.
// KTP = k-tiles per phase (1 or 2). 3 super-buffers x KTP k-tiles; per
// phase: counted vmcnt((ACH+2)*KTP) -> barrier -> stage phase+2 -> compute
// KTP k-tiles. KTP=2 halves barrier/vmcnt count (phase-overhead-bound
// regime); LDS 3*KTP*(BM+128)*32*2 B.
// MODE 0: plain store (bf16 via LDS writeout / fp32 direct).
// MODE 2: P = exp(scale*acc); cols >= lcv -> 0; bf16 writeout; rowsum atomics.
// MODE 3: fp32 LDS-staged writeout * (1/rowsum[row])  (fused normalize).
// ---------------------------------------------------------------------------
template <typename OutT, int MODE, int BM, int KTP>
static __device__ __forceinline__
void gemm_bt_body(int bx, int by, int zb, __hip_bfloat16* lds_pool,
                  const __hip_bfloat16* __restrict__ A,
                  const __hip_bfloat16* __restrict__ Bm,
                  OutT* __restrict__ C,
                  int K, int lda, int ldb, int ldc,
                  long batchStrideA, long batchStrideB, long batchStrideC,
                  float scale,
                  float* __restrict__ rowsum, int rowsumStride, int lcv)
{
    constexpr int MI  = BM / 32;        // frag rows per wave
    constexpr int ACH = BM / 64;        // A staging chunks per wave per k-tile
    constexpr int GPT = (ACH + 2) * KTP; // gloads per phase per wave
    constexpr int ATS = BM * 32;        // A elems per k-tile
    constexpr int BTS = 128 * 32;       // B elems per k-tile

    A  += (long)zb * batchStrideA;
    Bm += (long)zb * batchStrideB;
    C  += (long)zb * batchStrideC;
    const int NP = K / (32 * KTP);      // phases (>= 2 always here)

    const int tid  = threadIdx.x;
    const int lane = tid & 63;
    const int wave = tid >> 6;
    const int wm = (wave & 1) * (BM / 2);
    const int wn = (wave >> 1) * 64;
    const int rowBase = bx * BM;
    const int colBase = by * 128;

    __hip_bfloat16* AsP = lds_pool;                    // [3][KTP][ATS]
    __hip_bfloat16* BsP = lds_pool + 3 * KTP * ATS;    // [3][KTP][BTS]

    f32x4 acc[MI][4];
    #pragma unroll
    for (int i = 0; i < MI; ++i)
        #pragma unroll
        for (int j = 0; j < 4; ++j)
            acc[i][j] = (f32x4){0.f, 0.f, 0.f, 0.f};

    // Staging: wave w covers BM/4 A-rows + 32 B-rows as 16-row x 1024 B chunks.
    // Lane i: LDS lands at (row = i>>2, granule g = i&3). Pre-swizzle the
    // GLOBAL source granule: q = g ^ ((row>>1)&3)  (involution per row).
    const int srow = lane >> 2;
    const int scol = ((lane & 3) ^ ((lane >> 3) & 3)) * 8;   // swizzled source col
    const long ar0 = (long)(rowBase + wave * (BM / 4) + srow) * lda;
    const long ar1 = ar0 + 16l * lda;                         // ACH==2 only
    const long br0 = (long)(colBase + wave * 32 + srow) * ldb;
    const long br1 = br0 + 16l * ldb;

    const int mrow = lane & 15;         // fragment m/n index
    // Swizzled fragment k-offset (row bases ≡0 mod 16 -> lane-only term).
    const int koff = (((lane >> 4) ^ ((lane >> 1) & 3)) * 8);

    // Per wave each phase issues EXACTLY GPT global_load_lds ops.
    auto stage = [&](int buf, int ph) {
        #pragma unroll
        for (int j = 0; j < KTP; ++j) {
            const int kk = (ph * KTP + j) * 32 + scol;
            __hip_bfloat16* as = AsP + (buf * KTP + j) * ATS + wave * (BM / 4) * 32;
            __hip_bfloat16* bs = BsP + (buf * KTP + j) * BTS + wave * 1024;
            gload_lds16(A + ar0 + kk, as);
            if constexpr (ACH == 2)
                gload_lds16(A + ar1 + kk, as + 512);
            gload_lds16(Bm + br0 + kk, bs);
            gload_lds16(Bm + br1 + kk, bs + 512);
        }
    };

    // Prologue: phases 0,1 in flight. No barrier yet.
    stage(0, 0);
    stage(1, 1);

    int cur = 0;
    for (int ph = 0; ph < NP; ++ph) {
        // Drain OWN phase loads only; next phase's stay in flight across the
        // barrier (counted vmcnt — never drain to 0 in the main loop).
        if (ph + 1 < NP) {
            if constexpr (GPT == 3)
                asm volatile("s_waitcnt vmcnt(3)" ::: "memory");
            else if constexpr (GPT == 4)
                asm volatile("s_waitcnt vmcnt(4)" ::: "memory");
            else
                asm volatile("s_waitcnt vmcnt(6)" ::: "memory");
        } else {
            asm volatile("s_waitcnt vmcnt(0)" ::: "memory");
        }
        __builtin_amdgcn_s_barrier();
        // Stage phase+2 into buf (cur+2)%3: holds phase-1's tiles, whose
        // reads all completed before this barrier -> safe.
        if (ph + 2 < NP) {
            const int nxt2 = (cur >= 1) ? cur - 1 : cur + 2;   // (cur+2)%3
            stage(nxt2, ph + 2);
        }

        #pragma unroll
        for (int j = 0; j < KTP; ++j) {
            const __hip_bfloat16* as = AsP + (cur * KTP + j) * ATS;
            const __hip_bfloat16* bs = BsP + (cur * KTP + j) * BTS;
            short8 af[MI], bf[4];
            #pragma unroll
            for (int mi = 0; mi < MI; ++mi)
                af[mi] = *(const short8*)(as + (wm + mi * 16 + mrow) * 32 + koff);
            #pragma unroll
            for (int ni = 0; ni < 4; ++ni)
                bf[ni] = *(const short8*)(bs + (wn + ni * 16 + mrow) * 32 + koff);

            #pragma unroll
            for (int mi = 0; mi < MI; ++mi)
                #pragma unroll
                for (int ni = 0; ni < 4; ++ni)
                    acc[mi][ni] = __builtin_amdgcn_mfma_f32_16x16x32_bf16(
                        af[mi], bf[ni], acc[mi][ni], 0, 0, 0);
        }
        cur = (cur == 2) ? 0 : cur + 1;
    }

    // C/D layout (verified m89/m91): col = lane&15, row = (lane>>4)*4 + r
    const int crow0 = (lane >> 4) * 4;
    const int ccol  = lane & 15;

    if constexpr (MODE == 2) {
        // --- exp + compare-mask + rowsum; bf16 LDS-staged writeout ---
        __syncthreads();                   // pool safe: vmcnt(0) drained above
        __hip_bfloat16* cst = lds_pool;    // [128][136], granule^(row>>3)
        bool mk[4];
        #pragma unroll
        for (int ni = 0; ni < 4; ++ni)
            mk[ni] = (colBase + wn + ni * 16 + ccol) >= lcv;
        #pragma unroll
        for (int mi = 0; mi < MI; ++mi) {
            #pragma unroll
            for (int r = 0; r < 4; ++r) {
                const int row = wm + mi * 16 + crow0 + r;
                float rs = 0.f;
                #pragma unroll
                for (int ni = 0; ni < 4; ++ni) {
                    const int col = wn + ni * 16 + ccol;
                    const float e = mk[ni] ? 0.f
                                           : __expf(acc[mi][ni][r] * scale);
                    const __hip_bfloat16 pb = __float2bfloat16(e);
                    cst[row * 136 + (((col >> 3) ^ (row >> 3)) << 3) + (col & 7)] = pb;
                    rs += __bfloat162float(pb);
                }
                rs += __shfl_xor(rs, 1, 64);
                rs += __shfl_xor(rs, 2, 64);
                rs += __shfl_xor(rs, 4, 64);
                rs += __shfl_xor(rs, 8, 64);
                if ((lane & 15) == 0)
                    atomicAdd(&rowsum[(long)zb * rowsumStride + rowBase + row], rs);
            }
        }
        __syncthreads();
        const int g   = tid & 15;
        const int r4  = tid >> 4;
        const int lof = ((g ^ r4) << 3);
        #pragma unroll
        for (int k = 0; k < 8; ++k) {
            const int row = r4 * 8 + k;
            const short8 v = *(const short8*)(cst + row * 136 + lof);
            *(short8*)(&((__hip_bfloat16*)C)[(long)(rowBase + row) * ldc + colBase + g * 8]) = v;
        }
    } else if constexpr (MODE == 3) {
        // fp32 LDS-staged writeout with fused 1/rowsum normalize (Z output).
        // [64][136] f32 (stride 136 -> 2-way banks = free); then
        // ds_read_b128 + global_store_dwordx4 at 128B/row segments.
        __syncthreads();                   // pool safe: vmcnt(0) drained above
        float* fst = (float*)lds_pool;
        #pragma unroll
        for (int mi = 0; mi < MI; ++mi) {
            #pragma unroll
            for (int r = 0; r < 4; ++r) {
                const int row = wm + mi * 16 + crow0 + r;
                const float inv = 1.0f / rowsum[(long)zb * rowsumStride + rowBase + row];
                #pragma unroll
                for (int ni = 0; ni < 4; ++ni)
                    fst[row * 136 + wn + ni * 16 + ccol] = acc[mi][ni][r] * inv;
            }
        }
        __syncthreads();
        #pragma unroll
        for (int pass = 0; pass < 2; ++pass) {
            const int row = (tid >> 3) + pass * 32;
            #pragma unroll
            for (int k = 0; k < 4; ++k) {
                const int c4 = (tid & 7) + k * 8;       // float4 index 0..31
                const f32x4 v = *(const f32x4*)(fst + row * 136 + c4 * 4);
                *(f32x4*)(&((float*)C)[(long)(rowBase + row) * ldc + colBase + c4 * 4]) = v;
            }
        }
    } else if constexpr (sizeof(OutT) == 2) {
        // bf16 LDS-staged writeout (Q/K outputs)
        __syncthreads();
        __hip_bfloat16* cst = lds_pool;
        #pragma unroll
        for (int mi = 0; mi < MI; ++mi) {
            #pragma unroll
            for (int ni = 0; ni < 4; ++ni) {
                #pragma unroll
                for (int r = 0; r < 4; ++r) {
                    const int row = wm + mi * 16 + crow0 + r;
                    const int col = wn + ni * 16 + ccol;
                    cst[row * 136 + (((col >> 3) ^ (row >> 3)) << 3) + (col & 7)] =
                        __float2bfloat16(acc[mi][ni][r] * scale);
                }
            }
        }
        __syncthreads();
        const int g   = tid & 15;
        const int r4  = tid >> 4;
        const int lof = ((g ^ r4) << 3);
        #pragma unroll
        for (int k = 0; k < 8; ++k) {
            const int row = r4 * 8 + k;
            const short8 v = *(const short8*)(cst + row * 136 + lof);
            *(short8*)(&((__hip_bfloat16*)C)[(long)(rowBase + row) * ldc + colBase + g * 8]) = v;
        }
    } else {
        // fp32 direct stores
        #pragma unroll
        for (int mi = 0; mi < MI; ++mi) {
            #pragma unroll
            for (int ni = 0; ni < 4; ++ni) {
                #pragma unroll
                for (int r = 0; r < 4; ++r) {
                    const int row = rowBase + wm + mi * 16 + crow0 + r;
                    const int col = colBase + wn + ni * 16 + ccol;
                    ((float*)C)[(long)row * ldc + col] = acc[mi][ni][r] * scale;
                }
            }
        }
    }
}

// XCD-chunked swizzle (T1): remap so each XCD owns a contiguous grid chunk.
static __device__ __forceinline__ void xcd_swizzle(int& bx, int& by, int& bz)
{
    const int nwg = gridDim.x * gridDim.y * gridDim.z;
    bx = blockIdx.x; by = blockIdx.y; bz = blockIdx.z;
    if ((nwg & 7) == 0) {
        int lin = bx + gridDim.x * (by + gridDim.y * bz);
        lin = (lin & 7) * (nwg >> 3) + (lin >> 3);
        bx = lin % gridDim.x;
        const int t = lin / gridDim.x;
        by = t % gridDim.y;
        bz = t / gridDim.y;
    }
}

// ---------------------------------------------------------------------------
// Merged Q-GEMM + K-GEMM launch. Grid (160, 2, 1):
//   bx <  32: Q = Gbf @ Wq^T   [B*T=4096 rows, K=DG=768]
//   bx >= 32: K = Hbf_c @ Wk^T [B*L row cap, K=DH=1024]; lcpad row-exit
// ---------------------------------------------------------------------------
__global__ __launch_bounds__(256)
void qk_gemm_kernel(const __hip_bfloat16* __restrict__ Gbf,
                    const __hip_bfloat16* __restrict__ Wqbf,
                    __hip_bfloat16* __restrict__ Qbf,
                    const __hip_bfloat16* __restrict__ Hbf,
                    const __hip_bfloat16* __restrict__ Wkbf,
                    __hip_bfloat16* __restrict__ Kbf,
                    const int* __restrict__ lcpad,
                    int DG_, int DH_, int P_, int L_)
{
    __shared__ __align__(16) __hip_bfloat16 lds_pool[24576];
    int bx, by, bz;
    xcd_swizzle(bx, by, bz);
    if (bx < 32) {
        gemm_bt_body<__hip_bfloat16, 0, 128, 1>(bx, by, 0, lds_pool,
            Gbf, Wqbf, Qbf, DG_, DG_, DG_, P_, 0, 0, 0, 1.0f,
            nullptr, 0, 0);
    } else {
        const int rowBase = (bx - 32) * 128;
        const int bb = rowBase / L_;
        if (rowBase - bb * L_ >= lcpad[bb]) return;
        gemm_bt_body<__hip_bfloat16, 0, 128, 1>(bx - 32, by, 0, lds_pool,
            Hbf, Wkbf, Kbf, DH_, DH_, DH_, P_, 0, 0, 0, 1.0f,
            nullptr, 0, 0);
    }
}

// ---------------------------------------------------------------------------
// S-GEMM: P_c = exp(Q @ K_c^T * P^-0.5); cols >= Lc -> 0; rowsum atomics.
// ---------------------------------------------------------------------------
__global__ __launch_bounds__(256)
void s_gemm_kernel(const __hip_bfloat16* __restrict__ Qbf,
                   const __hip_bfloat16* __restrict__ Kbf,
                   __hip_bfloat16* __restrict__ Sb,
                   const int* __restrict__ lc, const int* __restrict__ lcpad,
                   float* __restrict__ rowsum,
                   int P_, int L_, int T_)
{
    __shared__ __align__(16) __hip_bfloat16 lds_pool[24576];
    int bx, by, bz;
    xcd_swizzle(bx, by, bz);
    if (by * 128 >= lcpad[bz]) return;   // masked-out col tile
    gemm_bt_body<__hip_bfloat16, 2, 128, 1>(bx, by, bz, lds_pool,
        Qbf, Kbf, Sb, P_, P_, P_, L_,
        (long)T_ * P_, (long)L_ * P_, (long)T_ * L_, 0.0625f,
        rowsum, T_, lc[bz]);
}

// ---------------------------------------------------------------------------
// Z-GEMM: Z = (P_c @ Ht_c^T) * (1/rowsum). 64x128 tiles (M-split, full
// compact K per WG), KTP=2 phase-pairing (72 KB LDS, 2 WGs/CU).
// ---------------------------------------------------------------------------
__global__ __launch_bounds__(256)
void z_gemm_kernel(const __hip_bfloat16* __restrict__ Sb,
                   const __hip_bfloat16* __restrict__ Ht,
                   float* __restrict__ Z,
                   const int* __restrict__ lcpad,
                   const float* __restrict__ rowsum,
                   int L_, int DH_, int T_)
{
    __shared__ __align__(16) __hip_bfloat16 lds_pool[36864];  // 72 KiB
    int bx, by, bz;
    xcd_swizzle(bx, by, bz);
    gemm_bt_body<float, 3, 64, 2>(bx, by, bz, lds_pool,
        Sb, Ht, Z, lcpad[bz], L_, L_, DH_,
        (long)T_ * L_, (long)DH_ * L_, (long)T_ * DH_, 1.0f,
        (float*)rowsum, T_, 0);
}

// ---------------------------------------------------------------------------
extern "C" void kernel_launch(void* const* d_in, const int* in_sizes, int n_in,
                              void* d_out, int out_size, void* d_ws, size_t ws_size,
                              hipStream_t stream)
{
    constexpr int B = 4, L = 4096, DH = 1024, T = 1024, DG = 768, P = 256;

    const float* H  = (const float*)d_in[0];
    const float* G  = (const float*)d_in[1];
    const void*  mask = d_in[2];
    const float* Wk = (const float*)d_in[3];
    const float* Wq = (const float*)d_in[4];
    for (int i = 0; i < n_in; ++i) {
        switch (in_sizes[i]) {
            case B * L * DH: H    = (const float*)d_in[i]; break;
            case B * T * DG: G    = (const float*)d_in[i]; break;
            case B * L:      mask = d_in[i];               break;
            case P * DH:     Wk   = (const float*)d_in[i]; break;
            case P * DG:     Wq   = (const float*)d_in[i]; break;
        }
    }
    float* Z = (float*)d_out;

    char* ws = (char*)d_ws;
    __hip_bfloat16* Hbf  = (__hip_bfloat16*)ws;                      // [0, 32 MiB) — compact rows
    __hip_bfloat16* Ht   = (__hip_bfloat16*)(ws + (32l << 20));      // [32, 64) — compact cols
    __hip_bfloat16* Gbf  = (__hip_bfloat16*)(ws + (64l << 20));      // [64, 70)
    __hip_bfloat16* Qbf  = (__hip_bfloat16*)(ws + (70l << 20));      // [70, 72)
    __hip_bfloat16* Kbf  = (__hip_bfloat16*)(ws + (72l << 20));      // [72, 80) — compact rows
    __hip_bfloat16* Wkbf = (__hip_bfloat16*)(ws + (80l << 20));      // 512 KiB
    __hip_bfloat16* Wqbf = (__hip_bfloat16*)(ws + (80l << 20) + (512l << 10)); // 384 KiB
    float*          rowsum    = (float*)(ws + (80l << 20) + (896l << 10));     // 16 KiB
    int*            lcBuf     = (int*)  (ws + (80l << 20) + (961l << 10));     // 16 B
    int*            lcpadBuf  = (int*)  (ws + (80l << 20) + (961l << 10) + 64);// 16 B
    unsigned short* idxBuf    = (unsigned short*)(ws + (80l << 20) + (962l << 10)); // 32 KiB
    __hip_bfloat16* Sb   = (__hip_bfloat16*)(ws + (81l << 20));      // [81, 113) — compact cols

    const dim3 blk(256);

    // 1) width + valid-l scan + rowsum zero (once; one block/batch)
    scan_kernel<<<dim3(B), blk, 0, stream>>>(
        mask, idxBuf, lcBuf, lcpadBuf, rowsum, L, T, B);

    // 2) fused prep: H gather/transpose (4096 blocks) + cvt Wk/Wq/G (3520)
    prep_all_kernel<<<dim3(7616), blk, 0, stream>>>(
        H, Hbf, Ht, idxBuf, lcBuf, lcpadBuf,
        Wk, (unsigned short*)Wkbf, Wq, (unsigned short*)Wqbf,
        G, (unsigned short*)Gbf, L, DH);

    // 3) Q = G @ Wq^T  and  K_c = Hbf_c @ Wk^T  in one launch
    qk_gemm_kernel<<<dim3(160, 2, 1), blk, 0, stream>>>(
        Gbf, Wqbf, Qbf, Hbf, Wkbf, Kbf, lcpadBuf, DG, DH, P, L);

    // 4) P_c = exp(Q @ K_c^T / 16), cols >= Lc zeroed; rowsum atomics
    s_gemm_kernel<<<dim3(T / 128, L / 128, B), blk, 0, stream>>>(
        Qbf, Kbf, Sb, lcBuf, lcpadBuf, rowsum, P, L, T);

    // 5) Z = (P_c @ Ht_c^T) / rowsum   64x128 tiles, KTP=2, direct store
    z_gemm_kernel<<<dim3(T / 64, DH / 128, B), blk, 0, stream>>>(
        Sb, Ht, Z, lcpadBuf, rowsum, L, DH, T);
}